// Round 13
// baseline (357.020 us; speedup 1.0000x reference)
//
#include <hip/hip_runtime.h>
#include <math.h>
#include <stdio.h>
#include <stdint.h>

#define GXD 272
#define GYD 112
#define GZD 272
#define NROT 36
#define CCLS (GXD*GZD)     /* 73984 = 289*256 */
#define CBLK (CCLS/256)    /* 289 cell blocks */
#define KSMP 1024          /* NUM_PROPOSAL*OVERSAMPLE */
#define NPROP 256
#define HSLOTS 2048        /* sampled-cell hash table slots */
#define YH 56              /* y-half size */
#define NBINS (GXD*2)      /* 544: (x-slice, y-half) bins */
#define SLICE (GYD*GZD)    /* 30464 cells per x-slice */
#define SVCAP 96           /* survivor capacity per row (spec E~36) */
#define BANDCAP 96         /* LDS band-candidate capacity in finalize */
#define AROWS 8            /* rows per phase-A unit (short blocks -> small host tails) */
#define AUNITS (CBLK * (KSMP/AROWS))   /* 289*128 = 36992 ballast units */
#define TH_SPEC 0xFFE00000u  /* speculative bits threshold: p = 2^-11 */
#define VC_INVALID 0xFFFFFFFFu

struct RotTab { float c[NROT]; float s[NROT]; };

__device__ __forceinline__ uint32_t cell_hash(int flat) {
    return ((uint32_t)flat * 2654435761u) >> 21;  // top 11 bits -> 0..2047
}

// rotl via single v_alignbit_b32: alignbit(x,x,s) = rotr(x,s); rotl(x,r)=rotr(x,32-r)
#define ROTL_AB(x, r) __builtin_amdgcn_alignbit((x), (x), 32u - (r))

// ---------------- threefry2x32, key (0,42), counter (0,i), out = o0^o1 ----------------
__device__ __forceinline__ uint32_t tf_bits(uint32_t i) {
    constexpr uint32_t K1  = 42u;
    constexpr uint32_t KS2 = 42u ^ 0x1BD11BDAu;
    uint32_t x0 = 0u, x1 = i + K1;                     // inj0 (k0 == 0)
#define TF_R(r)  { x0 += x1; x1 = ROTL_AB(x1, r); x1 ^= x0; }
#define TF_RI(r, I0, I1) { x1 += (I1); x0 = x0 + (I0) + x1; x1 = ROTL_AB(x1, r); x1 ^= x0; }
    TF_R(13) TF_R(15) TF_R(26) TF_R(6)
    TF_RI(17, K1,  KS2 + 1u)  TF_R(29) TF_R(16) TF_R(24)
    TF_RI(13, KS2, 2u)        TF_R(15) TF_R(26) TF_R(6)
    TF_RI(17, 0u,  K1 + 3u)   TF_R(29) TF_R(16) TF_R(24)
    TF_RI(13, K1,  KS2 + 4u)  TF_R(15) TF_R(26) TF_R(6)
#undef TF_R
#undef TF_RI
    return (x0 + KS2) ^ (x1 + 5u);                     // inj5 folded into output
}

__device__ __forceinline__ float uniform_from_bits(uint32_t b) {
    const float TINY = 1.1754943508222875e-38f; // np.finfo(float32).tiny
    float f = __uint_as_float((b >> 9) | 0x3f800000u) - 1.0f;
    float u = __fadd_rn(__fmul_rn(f, 1.0f), TINY);
    return fmaxf(TINY, u);
}

// gumbel = -log(-log(u)); f32 logs via double rounding (== correctly-rounded logf)
__device__ __forceinline__ float gumbel_from_u(float u) {
    float l1 = (float)log((double)u);
    float l2 = (float)log((double)(-l1));
    return -l2;
}

// ---------------- Phase A: speculative survivor recording (data-independent) ----------------
// MUST complete (all AUNITS) before k_finalize: the exactness check assumes every
// bits >= TH_SPEC hit is recorded. ALL ballast lives on the four pre-finalize hosts.
__device__ __forceinline__ void phaseA_unit(int unit, int* __restrict__ svcnt,
                                            uint2* __restrict__ svrec) {
    int cb = unit % CBLK;
    int rg = unit / CBLK;
    int c  = cb * 256 + threadIdx.x;
    int k0 = rg * AROWS;
    uint32_t i = (uint32_t)k0 * (uint32_t)CCLS + (uint32_t)c;
#pragma unroll 4
    for (int kk = 0; kk < AROWS; ++kk) {
        uint32_t bits = tf_bits(i);
        if (__builtin_expect(bits >= TH_SPEC, 0)) {
            int row = k0 + kk;
            int idx = atomicAdd(&svcnt[row], 1);
            if (idx < SVCAP) svrec[row * SVCAP + idx] = make_uint2((uint32_t)c, bits);
        }
        i += (uint32_t)CCLS;
    }
}

// ---- vote voxel helpers: MUST stay bit-identical across all passes ----
__device__ __forceinline__ bool vote_iy(float py, float oy, float c0y, int& iy) {
    float ty = __fadd_rn(py, oy);
    float vy = __fadd_rn(__fdiv_rn(__fsub_rn(ty, c0y), 0.03f), 0.5f);
    iy = (int)floorf(vy);
    return (iy >= 0 && iy < GYD);
}
__device__ __forceinline__ bool vote_xz(float px, float pz, float ox, float oz,
                                        float c, float s, float c0x, float c0z,
                                        int& ix, int& iz) {
    float rx = __fadd_rn(__fmul_rn(ox, c), __fmul_rn(oz, s));
    float rz = __fadd_rn(__fmul_rn(-ox, s), __fmul_rn(oz, c));
    float tx = __fadd_rn(px, rx);
    float tz = __fadd_rn(pz, rz);
    float vx = __fadd_rn(__fdiv_rn(__fsub_rn(tx, c0x), 0.03f), 0.5f);
    float vz = __fadd_rn(__fdiv_rn(__fsub_rn(tz, c0z), 0.03f), 0.5f);
    ix = (int)floorf(vx);
    iz = (int)floorf(vz);
    return (ix >= 0 && ix < GXD && iz >= 0 && iz < GZD);
}

// ---------------- K1a: count votes per bin + hist cache + VOTE CACHE  [+ ballast] ----------------
__global__ __launch_bounds__(256) void k_count_b(const float* __restrict__ pc, const float* __restrict__ xyz,
                          const float* __restrict__ corners, int N, RotTab rt,
                          int* __restrict__ bincnt, int* __restrict__ hblk,
                          uint32_t* __restrict__ vcache,
                          int nOrig, int unitBase, int* __restrict__ svcnt, uint2* __restrict__ svrec) {
    if ((int)blockIdx.x >= nOrig) { phaseA_unit(unitBase + (int)blockIdx.x - nOrig, svcnt, svrec); return; }
    __shared__ int h[NBINS];
    int tid = threadIdx.x;
    for (int j = tid; j < NBINS; j += 256) h[j] = 0;
    __syncthreads();
    int i = blockIdx.x * 256 + tid;
    bool act = false;
    float px=0, py=0, pz=0, ox=0, oy=0, oz=0, c0x=0, c0z=0;
    int ybit = 0, iyrel = 0;
    if (i < N) {
        px = pc[3*i]; py = pc[3*i+1]; pz = pc[3*i+2];
        ox = xyz[3*i]; oy = xyz[3*i+1]; oz = xyz[3*i+2];
        int iy;
        if (vote_iy(py, oy, corners[1], iy)) {
            act = true;
            ybit = (iy >= YH) ? 1 : 0;
            iyrel = iy - ybit*YH;
            c0x = corners[0]; c0z = corners[2];
        }
    }
    uint32_t* vc = vcache + ((size_t)blockIdx.x * NROT) * 256 + tid;
    for (int r = 0; r < NROT; ++r) {
        uint32_t v = VC_INVALID;
        if (act) {
            int ix, iz;
            if (vote_xz(px, pz, ox, oz, rt.c[r], rt.s[r], c0x, c0z, ix, iz)) {
                int bin = ix*2 + ybit;
                v = ((uint32_t)bin << 14) | (uint32_t)(iyrel*GZD + iz);
                atomicAdd(&h[bin], 1);
            }
        }
        vc[(size_t)r * 256] = v;
    }
    __syncthreads();
    int* hb = hblk + (size_t)blockIdx.x * NBINS;
    for (int j = tid; j < NBINS; j += 256) {
        int cnt = h[j];
        hb[j] = cnt;
        if (cnt) atomicAdd(&bincnt[j], cnt);
    }
}

// ---------------- K1b: parallel exclusive scan over 544 bins ----------------
__global__ __launch_bounds__(576) void k_prefix(const int* __restrict__ bincnt,
                         int* __restrict__ binbase, int* __restrict__ bincur) {
    __shared__ int sc[576];
    int tid = threadIdx.x;
    int v = (tid < NBINS) ? bincnt[tid] : 0;
    sc[tid] = v;
    __syncthreads();
    for (int off = 1; off < 576; off <<= 1) {
        int x = sc[tid];
        if (tid >= off) x += sc[tid - off];
        __syncthreads();
        sc[tid] = x;
        __syncthreads();
    }
    if (tid < NBINS) {
        int excl = sc[tid] - v;
        binbase[tid] = excl;
        bincur[tid] = excl;
    }
}

// ---------------- K1c: scatter cached votes -> packed records (i<<14 | rel)  [+ ballast] ----------------
__global__ __launch_bounds__(256) void k_binwrite_b(int N, int* __restrict__ bincur,
                          const int* __restrict__ hblk, const uint32_t* __restrict__ vcache,
                          uint32_t* __restrict__ vrec,
                          int nOrig, int unitBase, int* __restrict__ svcnt, uint2* __restrict__ svrec) {
    if ((int)blockIdx.x >= nOrig) { phaseA_unit(unitBase + (int)blockIdx.x - nOrig, svcnt, svrec); return; }
    __shared__ int h[NBINS];      // local rank cursor
    __shared__ int bbase[NBINS];  // this block's base per bin
    int tid = threadIdx.x;
    const int* hb = hblk + (size_t)blockIdx.x * NBINS;
    for (int j = tid; j < NBINS; j += 256) {
        int cnt = hb[j];
        bbase[j] = cnt ? atomicAdd(&bincur[j], cnt) : 0;
        h[j] = 0;
    }
    __syncthreads();
    uint32_t i = (uint32_t)(blockIdx.x * 256 + tid);
    const uint32_t* vc = vcache + ((size_t)blockIdx.x * NROT) * 256 + tid;
    uint32_t ish = i << 14;
    for (int r = 0; r < NROT; ++r) {
        uint32_t v = vc[(size_t)r * 256];
        if (v != VC_INVALID) {
            int bin = (int)(v >> 14);
            int rank = atomicAdd(&h[bin], 1);
            vrec[bbase[bin] + rank] = ish | (v & 0x3FFFu);
        }
    }
}

// ---------------- K1d: per-bin LDS accumulate + packed column-max atomicMax ----------------
__global__ __launch_bounds__(256) void k_accum(const int* __restrict__ binbase,
                          const int* __restrict__ bincnt,
                          const uint32_t* __restrict__ vrec,
                          const float* __restrict__ prob,
                          unsigned long long* __restrict__ packed) {
    __shared__ float tile[YH*GZD];   // 56*272*4 = 60928 B
    int b = blockIdx.x;
    int x = b >> 1, yh = b & 1;
    int tid = threadIdx.x;
    for (int j = tid; j < YH*GZD; j += 256) tile[j] = 0.0f;
    __syncthreads();
    int lo = binbase[b], n = bincnt[b];
    for (int j = lo + tid; j < lo + n; j += 256) {
        uint32_t rec = vrec[j];
        atomicAdd(&tile[rec & 0x3FFFu], prob[rec >> 14]);
    }
    __syncthreads();
    int ybase = yh * YH;
    for (int z = tid; z < GZD; z += 256) {
        float m = tile[z];
        int mi = 0;
        for (int y = 1; y < YH; ++y) {
            float v = tile[y*GZD + z];
            if (v > m) { m = v; mi = y; }
        }
        unsigned long long key = ((unsigned long long)__float_as_uint(m) << 32)
                               | (unsigned long long)(uint32_t)(0x7F - (ybase + mi));
        atomicMax(&packed[x*GZD + z], key);
    }
}

// ---------------- K2: decode packed -> logits/yidx; sum(dist)  [+ ballast] ----------------
__global__ __launch_bounds__(256) void k_colmax2_b(const unsigned long long* __restrict__ packed,
                         float* __restrict__ logits, int* __restrict__ yidx,
                         float* __restrict__ sumdist,
                         int nOrig, int unitBase, int* __restrict__ svcnt, uint2* __restrict__ svrec) {
    if ((int)blockIdx.x >= nOrig) { phaseA_unit(unitBase + (int)blockIdx.x - nOrig, svcnt, svrec); return; }
    int c = blockIdx.x * 256 + threadIdx.x;
    unsigned long long key = packed[c];
    float m = __uint_as_float((uint32_t)(key >> 32));
    int mi = 0x7F - (int)(uint32_t)(key & 0xFFFFFFFFu);
    float d = __fsqrt_rn(__fadd_rn(m, 1e-7f));
    yidx[c] = mi;
    logits[c] = (float)log((double)__fadd_rn(d, 1e-30f));
    __shared__ float sred[256];
    int tid = threadIdx.x;
    sred[tid] = d; __syncthreads();
    for (int off = 128; off > 0; off >>= 1) {
        if (tid < off) sred[tid] += sred[tid+off];
        __syncthreads();
    }
    if (tid == 0) atomicAdd(sumdist, sred[0]);
}

// ---------------- K2b: bth + hot-cell list  [+ ballast] ----------------
__global__ __launch_bounds__(256) void k_hotthresh_b(const float* __restrict__ logits,
                                                     const float* __restrict__ sumdist,
                                                     uint32_t* __restrict__ bth,
                                                     int* __restrict__ hotcnt, int* __restrict__ hotlist,
                                                     int nOrig, int unitBase,
                                                     int* __restrict__ svcnt, uint2* __restrict__ svrec) {
    if ((int)blockIdx.x >= nOrig) { phaseA_unit(unitBase + (int)blockIdx.x - nOrig, svcnt, svrec); return; }
    int c = blockIdx.x * 256 + threadIdx.x;
    double B0 = log((double)*sumdist) - 3.0;
    double t = exp(-exp((double)logits[c] - (B0 - 0.05)));
    long long k_th = (long long)floor(t * 8388608.0) - 2;
    uint32_t b;
    if (k_th <= 0)              b = 0u;           // everything survives
    else if (k_th >= 8388608LL) b = 0xFFFFFFFFu;  // ~nothing survives (over-include, harmless)
    else                        b = (uint32_t)k_th << 9;
    bth[c] = b;
    if (b < TH_SPEC) {
        int idx = atomicAdd(hotcnt, 1);
        hotlist[idx] = c;
    }
}

// ---------------- K3f: per-row fused band-scan + argmax + exactness check + table insert ----------------
// 256 threads/row (R9's 64-thread fusion was TLP-starved). Band candidates
// (bth <= bits < TH_SPEC) collected in LDS; argmax over spec records + band.
// Exact: winner v > B0-0.05 => recorded in spec (bits>=TH_SPEC) or band; else full scan.
__global__ __launch_bounds__(256) void k_finalize(const float* __restrict__ logits,
                                                 const float* __restrict__ sumdist,
                                                 const int* __restrict__ svcnt,
                                                 const uint2* __restrict__ svrec,
                                                 const uint32_t* __restrict__ bth,
                                                 const int* __restrict__ hotlist,
                                                 const int* __restrict__ hotcnt,
                                                 const int* __restrict__ yidx,
                                                 int* __restrict__ hkeys,
                                                 int* __restrict__ samples) {
    int k = blockIdx.x;
    int tid = threadIdx.x;
    __shared__ uint2 band[BANDCAP];
    __shared__ int bandcnt;
    __shared__ float sv[256];
    __shared__ int   si[256];
    if (tid == 0) bandcnt = 0;
    __syncthreads();
    uint32_t base = (uint32_t)k * (uint32_t)CCLS;
    int nhot = *hotcnt;
    for (int j = tid; j < nhot; j += 256) {
        int c = hotlist[j];
        uint32_t bits = tf_bits(base + (uint32_t)c);
        if (bits >= bth[c] && bits < TH_SPEC) {
            int idx = atomicAdd(&bandcnt, 1);
            if (idx < BANDCAP) band[idx] = make_uint2((uint32_t)c, bits);
        }
    }
    __syncthreads();
    int n  = svcnt[k];
    int nb = bandcnt;
    double B0 = log((double)*sumdist) - 3.0;
    float best = -INFINITY; int bc = 0x7fffffff;
    bool full = (n > SVCAP) || (nb > BANDCAP);
    if (!full) {
        for (int j = tid; j < n; j += 256) {
            uint2 rec = svrec[k * SVCAP + j];
            int c = (int)rec.x;
            float v = __fadd_rn(gumbel_from_u(uniform_from_bits(rec.y)), logits[c]);
            if (v > best || (v == best && c < bc)) { best = v; bc = c; }
        }
        for (int j = tid; j < nb; j += 256) {
            uint2 rec = band[j];
            int c = (int)rec.x;
            float v = __fadd_rn(gumbel_from_u(uniform_from_bits(rec.y)), logits[c]);
            if (v > best || (v == best && c < bc)) { best = v; bc = c; }
        }
        sv[tid] = best; si[tid] = bc; __syncthreads();
        for (int off = 128; off > 0; off >>= 1) {
            if (tid < off) {
                float v2 = sv[tid+off]; int i2 = si[tid+off];
                if (v2 > sv[tid] || (v2 == sv[tid] && i2 < si[tid])) { sv[tid] = v2; si[tid] = i2; }
            }
            __syncthreads();
        }
        best = sv[0]; bc = si[0];
        __syncthreads();   // all reads of sv[0]/si[0] done before any LDS reuse
        if (!((double)best > B0 - 0.05)) full = true;   // winner might be unrecorded
    }
    if (full) {
        best = -INFINITY; bc = 0x7fffffff;
        for (int c = tid; c < CCLS; c += 256) {
            float v = __fadd_rn(gumbel_from_u(uniform_from_bits(tf_bits(base + (uint32_t)c))), logits[c]);
            if (v > best || (v == best && c < bc)) { best = v; bc = c; }
        }
        sv[tid] = best; si[tid] = bc; __syncthreads();
        for (int off = 128; off > 0; off >>= 1) {
            if (tid < off) {
                float v2 = sv[tid+off]; int i2 = si[tid+off];
                if (v2 > sv[tid] || (v2 == sv[tid] && i2 < si[tid])) { sv[tid] = v2; si[tid] = i2; }
            }
            __syncthreads();
        }
        best = sv[0]; bc = si[0];
    }
    if (tid == 0) {
        samples[k] = bc;
        // hash insert; empty sentinel = 0, stored key = flat+1 (zeroed in main memset)
        int xi = bc / GZD, zi = bc % GZD;
        int yi = yidx[bc];
        int key = (xi*GYD + yi)*GZD + zi + 1;
        uint32_t h = cell_hash(key - 1);
        for (;;) {
            int prev = atomicCAS(&hkeys[h], 0, key);
            if (prev == 0 || prev == key) break;
            h = (h + 1) & (HSLOTS - 1);
        }
    }
}

// ---------------- K3c: record-driven scale accumulation (no ballast: runs post-finalize) ----------------
__global__ __launch_bounds__(256) void k_scale_b(const int* __restrict__ binbase,
                          const int* __restrict__ bincnt,
                          const uint32_t* __restrict__ vrec,
                          const float* __restrict__ prob, const float* __restrict__ scale,
                          const int* __restrict__ hkeys, float* __restrict__ gsmall) {
    __shared__ int lk[HSLOTS];
    for (int j = threadIdx.x; j < HSLOTS; j += 256) lk[j] = hkeys[j];
    __syncthreads();
    int b = blockIdx.x;
    int x = b >> 1, ybit = b & 1;
    int fbase = x * SLICE + ybit * (YH*GZD) + 1;   // +1: stored keys are flat+1
    int lo = binbase[b], n = bincnt[b];
    for (int j = lo + threadIdx.x; j < lo + n; j += 256) {
        uint32_t rec = vrec[j];
        int key = fbase + (int)(rec & 0x3FFFu);
        uint32_t h = cell_hash(key - 1);
        int slot = -1;
        for (;;) {
            int kk = lk[h];
            if (kk == key) { slot = (int)h; break; }
            if (kk == 0) break;
            h = (h + 1) & (HSLOTS - 1);
        }
        if (slot < 0) continue;
        int i = (int)(rec >> 14);
        float w0 = prob[i];
        atomicAdd(&gsmall[3*slot+0], __fmul_rn(w0, scale[3*i]));
        atomicAdd(&gsmall[3*slot+1], __fmul_rn(w0, scale[3*i+1]));
        atomicAdd(&gsmall[3*slot+2], __fmul_rn(w0, scale[3*i+2]));
    }
}

// ---------------- K4: one block per sample — world loc, scale, keep ----------------
__global__ __launch_bounds__(256) void k_post(const unsigned long long* __restrict__ packed,
                       const int* __restrict__ hkeys, const float* __restrict__ gsmall,
                       const int* __restrict__ yidx, const int* __restrict__ samples,
                       const float* __restrict__ corners, const float* __restrict__ vp, int M,
                       float* __restrict__ world, float* __restrict__ scv, int* __restrict__ keep) {
    int k = blockIdx.x;
    int tid = threadIdx.x;
    int s = samples[k];
    int xi = s / GZD, zi = s % GZD;
    int yi = yidx[s];
    float wx = __fadd_rn(__fmul_rn((float)xi, 0.03f), corners[0]);
    float wy = __fadd_rn(__fmul_rn((float)yi, 0.03f), corners[1]);
    float wz = __fadd_rn(__fmul_rn((float)zi, 0.03f), corners[2]);

    float dmin = INFINITY;
    for (int j = tid; j < M; j += 256) {
        float dx = __fsub_rn(wx, vp[3*j]);
        float dy = __fsub_rn(wy, vp[3*j+1]);
        float dz = __fsub_rn(wz, vp[3*j+2]);
        float sq = __fadd_rn(__fadd_rn(__fmul_rn(dx,dx), __fmul_rn(dy,dy)), __fmul_rn(dz,dz));
        dmin = fminf(dmin, __fsqrt_rn(sq));
    }
    __shared__ float sm[256];
    sm[tid] = dmin; __syncthreads();
    for (int off = 128; off > 0; off >>= 1) {
        if (tid < off) sm[tid] = fminf(sm[tid], sm[tid+off]);
        __syncthreads();
    }
    if (tid == 0) {
        world[3*k] = wx; world[3*k+1] = wy; world[3*k+2] = wz;
        int key = (xi*GYD + yi)*GZD + zi + 1;
        uint32_t h = cell_hash(key - 1);
        while (hkeys[h] != key) h = (h + 1) & (HSLOTS - 1);  // guaranteed present
        float m = __uint_as_float((uint32_t)(packed[s] >> 32));
        float go = __fadd_rn(m, 1e-7f);
        scv[3*k+0] = __fdiv_rn(gsmall[3*h+0], go);
        scv[3*k+1] = __fdiv_rn(gsmall[3*h+1], go);
        scv[3*k+2] = __fdiv_rn(gsmall[3*h+2], go);
        keep[k] = (sm[0] < 0.3f) ? 1 : 0;
    }
}

// ---------------- K5: stable 0/1 selection via parallel prefix-sum ----------------
__global__ __launch_bounds__(256) void k_select(const float* __restrict__ world,
                                                const float* __restrict__ scv,
                                                const int* __restrict__ keep,
                                                float* __restrict__ out) {
    __shared__ int kp[KSMP];
    __shared__ int tsum[256];
    __shared__ int sel[NPROP];
    __shared__ int anyk;
    int tid = threadIdx.x;
    if (tid == 0) anyk = 0;
    __syncthreads();
    int a = 0;
    for (int j = tid; j < KSMP; j += 256) { int v = keep[j]; kp[j] = v; a |= v; }
    if (a) anyk = 1;           // benign race, all writers store 1
    __syncthreads();
    int any = anyk;
    int j0 = tid * 4;
    int k0v = any ? kp[j0]   : 1;
    int k1v = any ? kp[j0+1] : 1;
    int k2v = any ? kp[j0+2] : 1;
    int k3v = any ? kp[j0+3] : 1;
    int s0 = k0v, s1 = s0 + k1v, s2 = s1 + k2v, s3 = s2 + k3v;
    tsum[tid] = s3;
    __syncthreads();
    for (int off = 1; off < 256; off <<= 1) {
        int x = tsum[tid];
        if (tid >= off) x += tsum[tid - off];
        __syncthreads();
        tsum[tid] = x;
        __syncthreads();
    }
    int base = (tid > 0) ? tsum[tid-1] : 0;
    int nk = tsum[255];  // total kept
    int inc[4] = { base + s0, base + s1, base + s2, base + s3 };
    int kv[4]  = { k0v, k1v, k2v, k3v };
    for (int q = 0; q < 4; ++q) {
        int j = j0 + q;
        int slot = kv[q] ? (inc[q] - 1) : (nk + j - inc[q]);
        if (slot < NPROP) sel[slot] = j;
    }
    __syncthreads();
    if (tid < NPROP) {
        int sidx = sel[tid];
        out[3*tid+0] = world[3*sidx+0];
        out[3*tid+1] = world[3*sidx+1];
        out[3*tid+2] = world[3*sidx+2];
        out[3*NPROP + tid] = 0.0f;                 // probs
        out[4*NPROP + 3*tid + 0] = scv[3*sidx+0];
        out[4*NPROP + 3*tid + 1] = scv[3*sidx+1];
        out[4*NPROP + 3*tid + 2] = scv[3*sidx+2];
    }
}

extern "C" void kernel_launch(void* const* d_in, const int* in_sizes, int n_in,
                              void* d_out, int out_size, void* d_ws, size_t ws_size,
                              hipStream_t stream) {
    const float* pc      = (const float*)d_in[0];
    const float* xyz     = (const float*)d_in[1];
    const float* scale   = (const float*)d_in[2];
    const float* prob    = (const float*)d_in[3];
    const float* corners = (const float*)d_in[4];
    const float* vp      = (const float*)d_in[5];
    int N = in_sizes[0] / 3;
    int M = in_sizes[5] / 3;
    int pblocks = (N + 255) / 256;
    int NV = pblocks * 256 * NROT;   // vcache/vrec capacity (full blocks)
    if (N > (1 << 17)) {   // vrec packing requires i < 2^17 (ref N = 100000)
        fprintf(stderr, "kernel_launch: N %d exceeds packing limit\n", N);
        return;
    }

    // ---- zeroed region (single memset): sumdist..gsmall + hkeys (0-sentinel) ----
    float* sumdist = (float*)d_ws;                     // 1
    int*   bincnt  = (int*)(sumdist + 1);              // NBINS
    int*   svcnt   = bincnt + NBINS;                   // KSMP
    int*   hotcnt  = svcnt + KSMP;                     // 1 (also 8B-align pad)
    unsigned long long* packed = (unsigned long long*)(hotcnt + 1);  // CCLS u64
    float* gsmall  = (float*)(packed + CCLS);          // 3*HSLOTS
    int*   hkeys   = (int*)(gsmall + 3*HSLOTS);        // HSLOTS (0 = empty)
    size_t zero_bytes = (size_t)((char*)(hkeys + HSLOTS) - (char*)sumdist);
    // ---- rest ----
    int*   binbase = hkeys + HSLOTS;
    int*   bincur  = binbase + NBINS;
    float* logits  = (float*)(bincur + NBINS);
    uint32_t* bth  = (uint32_t*)(logits + CCLS);
    int*   yidx    = (int*)(bth + CCLS);
    int*   samples = yidx + CCLS;
    float* world   = (float*)(samples + KSMP);
    float* scv     = world + 3*KSMP;
    int*   keep    = (int*)(scv + 3*KSMP);
    uint2* svrec   = (uint2*)(((uintptr_t)(keep + KSMP) + 15) & ~(uintptr_t)15);
    int*   hotlist = (int*)(svrec + (size_t)KSMP * SVCAP);   // CCLS
    int*   hblk    = hotlist + CCLS;                         // pblocks*NBINS
    uint32_t* vcache = (uint32_t*)(((uintptr_t)(hblk + (size_t)pblocks*NBINS) + 15) & ~(uintptr_t)15);
    uint32_t* vrec = vcache + NV;
    size_t need = (size_t)((char*)(vrec + NV) - (char*)d_ws);
    if (ws_size < need) {
        fprintf(stderr, "kernel_launch: ws_size %zu < needed %zu\n", ws_size, need);
        return;
    }

    hipMemsetAsync(sumdist, 0, zero_bytes, stream);    // single memset (~630 KB)

    // rotation table: f32 theta chain exactly as reference, cos/sin in double -> f32
    RotTab rt;
    const float twopi = (float)(2.0 * M_PI);
    for (int r = 0; r < NROT; ++r) {
        float th = (twopi * (float)r) / 36.0f;
        rt.c[r] = (float)cos((double)th);
        rt.s[r] = (float)sin((double)th);
    }

    // phase-A ballast: ALL units on the four PRE-finalize hosts (sum == AUNITS = 36992)
    const int BAL1 = 11200, BAL2 = 11200, BAL3 = 7600;
    const int BAL4 = AUNITS - BAL1 - BAL2 - BAL3;   // 6992

    k_count_b<<<pblocks + BAL1, 256, 0, stream>>>(pc, xyz, corners, N, rt, bincnt, hblk, vcache,
                                                  pblocks, 0, svcnt, svrec);
    k_prefix<<<1, 576, 0, stream>>>(bincnt, binbase, bincur);
    k_binwrite_b<<<pblocks + BAL2, 256, 0, stream>>>(N, bincur, hblk, vcache, vrec,
                                                     pblocks, BAL1, svcnt, svrec);
    k_accum<<<NBINS, 256, 0, stream>>>(binbase, bincnt, vrec, prob, packed);
    k_colmax2_b<<<CBLK + BAL3, 256, 0, stream>>>(packed, logits, yidx, sumdist,
                                                 CBLK, BAL1 + BAL2, svcnt, svrec);
    k_hotthresh_b<<<CBLK + BAL4, 256, 0, stream>>>(logits, sumdist, bth, hotcnt, hotlist,
                                                   CBLK, BAL1 + BAL2 + BAL3, svcnt, svrec);
    k_finalize<<<KSMP, 256, 0, stream>>>(logits, sumdist, svcnt, svrec, bth, hotlist, hotcnt,
                                         yidx, hkeys, samples);
    k_scale_b<<<NBINS, 256, 0, stream>>>(binbase, bincnt, vrec, prob, scale, hkeys, gsmall);
    k_post<<<KSMP, 256, 0, stream>>>(packed, hkeys, gsmall, yidx, samples, corners, vp, M, world, scv, keep);
    k_select<<<1, 256, 0, stream>>>(world, scv, keep, (float*)d_out);
}

// Round 14
// 350.313 us; speedup vs baseline: 1.0191x; 1.0191x over previous
//
#include <hip/hip_runtime.h>
#include <math.h>
#include <stdio.h>
#include <stdint.h>

#define GXD 272
#define GYD 112
#define GZD 272
#define NROT 36
#define CCLS (GXD*GZD)     /* 73984 = 289*256 */
#define CBLK (CCLS/256)    /* 289 cell blocks */
#define KSMP 1024          /* NUM_PROPOSAL*OVERSAMPLE */
#define NPROP 256
#define HSLOTS 2048        /* sampled-cell hash table slots */
#define YH 56              /* y-half size */
#define NBINS (GXD*2)      /* 544: (x-slice, y-half) bins */
#define SLICE (GYD*GZD)    /* 30464 cells per x-slice */
#define SVCAP 96           /* survivor capacity per row (spec E~36) */
#define BANDCAP 96         /* LDS band-candidate capacity in finalize */
#define AROWS 32           /* rows per phase-A unit (R13: 8 regressed hosts +6us) */
#define AUNITS (CBLK * (KSMP/AROWS))   /* 289*32 = 9248 ballast units */
#define TH_SPEC 0xFFE00000u  /* speculative bits threshold: p = 2^-11 */
#define VC_INVALID 0xFFFFFFFFu

struct RotTab { float c[NROT]; float s[NROT]; };

__device__ __forceinline__ uint32_t cell_hash(int flat) {
    return ((uint32_t)flat * 2654435761u) >> 21;  // top 11 bits -> 0..2047
}

// rotl via single v_alignbit_b32: alignbit(x,x,s) = rotr(x,s); rotl(x,r)=rotr(x,32-r)
#define ROTL_AB(x, r) __builtin_amdgcn_alignbit((x), (x), 32u - (r))

// ---------------- threefry2x32, key (0,42), counter (0,i), out = o0^o1 ----------------
__device__ __forceinline__ uint32_t tf_bits(uint32_t i) {
    constexpr uint32_t K1  = 42u;
    constexpr uint32_t KS2 = 42u ^ 0x1BD11BDAu;
    uint32_t x0 = 0u, x1 = i + K1;                     // inj0 (k0 == 0)
#define TF_R(r)  { x0 += x1; x1 = ROTL_AB(x1, r); x1 ^= x0; }
#define TF_RI(r, I0, I1) { x1 += (I1); x0 = x0 + (I0) + x1; x1 = ROTL_AB(x1, r); x1 ^= x0; }
    TF_R(13) TF_R(15) TF_R(26) TF_R(6)
    TF_RI(17, K1,  KS2 + 1u)  TF_R(29) TF_R(16) TF_R(24)
    TF_RI(13, KS2, 2u)        TF_R(15) TF_R(26) TF_R(6)
    TF_RI(17, 0u,  K1 + 3u)   TF_R(29) TF_R(16) TF_R(24)
    TF_RI(13, K1,  KS2 + 4u)  TF_R(15) TF_R(26) TF_R(6)
#undef TF_R
#undef TF_RI
    return (x0 + KS2) ^ (x1 + 5u);                     // inj5 folded into output
}

__device__ __forceinline__ float uniform_from_bits(uint32_t b) {
    const float TINY = 1.1754943508222875e-38f; // np.finfo(float32).tiny
    float f = __uint_as_float((b >> 9) | 0x3f800000u) - 1.0f;
    float u = __fadd_rn(__fmul_rn(f, 1.0f), TINY);
    return fmaxf(TINY, u);
}

// gumbel = -log(-log(u)); f32 logs via double rounding (== correctly-rounded logf)
__device__ __forceinline__ float gumbel_from_u(float u) {
    float l1 = (float)log((double)u);
    float l2 = (float)log((double)(-l1));
    return -l2;
}

// ---------------- Phase A: speculative survivor recording (data-independent) ----------------
// MUST complete (all AUNITS) before k_finalize: the exactness check assumes every
// bits >= TH_SPEC hit is recorded. ALL ballast lives on the four pre-finalize hosts.
__device__ __forceinline__ void phaseA_unit(int unit, int* __restrict__ svcnt,
                                            uint2* __restrict__ svrec) {
    int cb = unit % CBLK;
    int rg = unit / CBLK;
    int c  = cb * 256 + threadIdx.x;
    int k0 = rg * AROWS;
    uint32_t i = (uint32_t)k0 * (uint32_t)CCLS + (uint32_t)c;
#pragma unroll 4
    for (int kk = 0; kk < AROWS; ++kk) {
        uint32_t bits = tf_bits(i);
        if (__builtin_expect(bits >= TH_SPEC, 0)) {
            int row = k0 + kk;
            int idx = atomicAdd(&svcnt[row], 1);
            if (idx < SVCAP) svrec[row * SVCAP + idx] = make_uint2((uint32_t)c, bits);
        }
        i += (uint32_t)CCLS;
    }
}

// ---- vote voxel helpers: MUST stay bit-identical across all passes ----
__device__ __forceinline__ bool vote_iy(float py, float oy, float c0y, int& iy) {
    float ty = __fadd_rn(py, oy);
    float vy = __fadd_rn(__fdiv_rn(__fsub_rn(ty, c0y), 0.03f), 0.5f);
    iy = (int)floorf(vy);
    return (iy >= 0 && iy < GYD);
}
__device__ __forceinline__ bool vote_xz(float px, float pz, float ox, float oz,
                                        float c, float s, float c0x, float c0z,
                                        int& ix, int& iz) {
    float rx = __fadd_rn(__fmul_rn(ox, c), __fmul_rn(oz, s));
    float rz = __fadd_rn(__fmul_rn(-ox, s), __fmul_rn(oz, c));
    float tx = __fadd_rn(px, rx);
    float tz = __fadd_rn(pz, rz);
    float vx = __fadd_rn(__fdiv_rn(__fsub_rn(tx, c0x), 0.03f), 0.5f);
    float vz = __fadd_rn(__fdiv_rn(__fsub_rn(tz, c0z), 0.03f), 0.5f);
    ix = (int)floorf(vx);
    iz = (int)floorf(vz);
    return (ix >= 0 && ix < GXD && iz >= 0 && iz < GZD);
}

// ---------------- K1a: count votes per bin + hist cache + VOTE CACHE  [+ ballast] ----------------
__global__ __launch_bounds__(256) void k_count_b(const float* __restrict__ pc, const float* __restrict__ xyz,
                          const float* __restrict__ corners, int N, RotTab rt,
                          int* __restrict__ bincnt, int* __restrict__ hblk,
                          uint32_t* __restrict__ vcache,
                          int nOrig, int unitBase, int* __restrict__ svcnt, uint2* __restrict__ svrec) {
    if ((int)blockIdx.x >= nOrig) { phaseA_unit(unitBase + (int)blockIdx.x - nOrig, svcnt, svrec); return; }
    __shared__ int h[NBINS];
    int tid = threadIdx.x;
    for (int j = tid; j < NBINS; j += 256) h[j] = 0;
    __syncthreads();
    int i = blockIdx.x * 256 + tid;
    bool act = false;
    float px=0, py=0, pz=0, ox=0, oy=0, oz=0, c0x=0, c0z=0;
    int ybit = 0, iyrel = 0;
    if (i < N) {
        px = pc[3*i]; py = pc[3*i+1]; pz = pc[3*i+2];
        ox = xyz[3*i]; oy = xyz[3*i+1]; oz = xyz[3*i+2];
        int iy;
        if (vote_iy(py, oy, corners[1], iy)) {
            act = true;
            ybit = (iy >= YH) ? 1 : 0;
            iyrel = iy - ybit*YH;
            c0x = corners[0]; c0z = corners[2];
        }
    }
    uint32_t* vc = vcache + ((size_t)blockIdx.x * NROT) * 256 + tid;
    for (int r = 0; r < NROT; ++r) {
        uint32_t v = VC_INVALID;
        if (act) {
            int ix, iz;
            if (vote_xz(px, pz, ox, oz, rt.c[r], rt.s[r], c0x, c0z, ix, iz)) {
                int bin = ix*2 + ybit;
                v = ((uint32_t)bin << 14) | (uint32_t)(iyrel*GZD + iz);
                atomicAdd(&h[bin], 1);
            }
        }
        vc[(size_t)r * 256] = v;
    }
    __syncthreads();
    int* hb = hblk + (size_t)blockIdx.x * NBINS;
    for (int j = tid; j < NBINS; j += 256) {
        int cnt = h[j];
        hb[j] = cnt;
        if (cnt) atomicAdd(&bincnt[j], cnt);
    }
}

// ---------------- K1b: parallel exclusive scan over 544 bins ----------------
__global__ __launch_bounds__(576) void k_prefix(const int* __restrict__ bincnt,
                         int* __restrict__ binbase, int* __restrict__ bincur) {
    __shared__ int sc[576];
    int tid = threadIdx.x;
    int v = (tid < NBINS) ? bincnt[tid] : 0;
    sc[tid] = v;
    __syncthreads();
    for (int off = 1; off < 576; off <<= 1) {
        int x = sc[tid];
        if (tid >= off) x += sc[tid - off];
        __syncthreads();
        sc[tid] = x;
        __syncthreads();
    }
    if (tid < NBINS) {
        int excl = sc[tid] - v;
        binbase[tid] = excl;
        bincur[tid] = excl;
    }
}

// ---------------- K1c: scatter cached votes -> packed records (i<<14 | rel)  [+ ballast] ----------------
__global__ __launch_bounds__(256) void k_binwrite_b(int N, int* __restrict__ bincur,
                          const int* __restrict__ hblk, const uint32_t* __restrict__ vcache,
                          uint32_t* __restrict__ vrec,
                          int nOrig, int unitBase, int* __restrict__ svcnt, uint2* __restrict__ svrec) {
    if ((int)blockIdx.x >= nOrig) { phaseA_unit(unitBase + (int)blockIdx.x - nOrig, svcnt, svrec); return; }
    __shared__ int h[NBINS];      // local rank cursor
    __shared__ int bbase[NBINS];  // this block's base per bin
    int tid = threadIdx.x;
    const int* hb = hblk + (size_t)blockIdx.x * NBINS;
    for (int j = tid; j < NBINS; j += 256) {
        int cnt = hb[j];
        bbase[j] = cnt ? atomicAdd(&bincur[j], cnt) : 0;
        h[j] = 0;
    }
    __syncthreads();
    uint32_t i = (uint32_t)(blockIdx.x * 256 + tid);
    const uint32_t* vc = vcache + ((size_t)blockIdx.x * NROT) * 256 + tid;
    uint32_t ish = i << 14;
    for (int r = 0; r < NROT; ++r) {
        uint32_t v = vc[(size_t)r * 256];
        if (v != VC_INVALID) {
            int bin = (int)(v >> 14);
            int rank = atomicAdd(&h[bin], 1);
            vrec[bbase[bin] + rank] = ish | (v & 0x3FFFu);
        }
    }
}

// ---------------- K1d: per-bin LDS accumulate + packed column-max atomicMax ----------------
__global__ __launch_bounds__(256) void k_accum(const int* __restrict__ binbase,
                          const int* __restrict__ bincnt,
                          const uint32_t* __restrict__ vrec,
                          const float* __restrict__ prob,
                          unsigned long long* __restrict__ packed) {
    __shared__ float tile[YH*GZD];   // 56*272*4 = 60928 B
    int b = blockIdx.x;
    int x = b >> 1, yh = b & 1;
    int tid = threadIdx.x;
    for (int j = tid; j < YH*GZD; j += 256) tile[j] = 0.0f;
    __syncthreads();
    int lo = binbase[b], n = bincnt[b];
    for (int j = lo + tid; j < lo + n; j += 256) {
        uint32_t rec = vrec[j];
        atomicAdd(&tile[rec & 0x3FFFu], prob[rec >> 14]);
    }
    __syncthreads();
    int ybase = yh * YH;
    for (int z = tid; z < GZD; z += 256) {
        float m = tile[z];
        int mi = 0;
        for (int y = 1; y < YH; ++y) {
            float v = tile[y*GZD + z];
            if (v > m) { m = v; mi = y; }
        }
        unsigned long long key = ((unsigned long long)__float_as_uint(m) << 32)
                               | (unsigned long long)(uint32_t)(0x7F - (ybase + mi));
        atomicMax(&packed[x*GZD + z], key);
    }
}

// ---------------- K2: decode packed -> logits/yidx; sum(dist)  [+ ballast] ----------------
__global__ __launch_bounds__(256) void k_colmax2_b(const unsigned long long* __restrict__ packed,
                         float* __restrict__ logits, int* __restrict__ yidx,
                         float* __restrict__ sumdist,
                         int nOrig, int unitBase, int* __restrict__ svcnt, uint2* __restrict__ svrec) {
    if ((int)blockIdx.x >= nOrig) { phaseA_unit(unitBase + (int)blockIdx.x - nOrig, svcnt, svrec); return; }
    int c = blockIdx.x * 256 + threadIdx.x;
    unsigned long long key = packed[c];
    float m = __uint_as_float((uint32_t)(key >> 32));
    int mi = 0x7F - (int)(uint32_t)(key & 0xFFFFFFFFu);
    float d = __fsqrt_rn(__fadd_rn(m, 1e-7f));
    yidx[c] = mi;
    logits[c] = (float)log((double)__fadd_rn(d, 1e-30f));
    __shared__ float sred[256];
    int tid = threadIdx.x;
    sred[tid] = d; __syncthreads();
    for (int off = 128; off > 0; off >>= 1) {
        if (tid < off) sred[tid] += sred[tid+off];
        __syncthreads();
    }
    if (tid == 0) atomicAdd(sumdist, sred[0]);
}

// ---------------- K2b: bth + hot-cell list  [+ ballast] ----------------
__global__ __launch_bounds__(256) void k_hotthresh_b(const float* __restrict__ logits,
                                                     const float* __restrict__ sumdist,
                                                     uint32_t* __restrict__ bth,
                                                     int* __restrict__ hotcnt, int* __restrict__ hotlist,
                                                     int nOrig, int unitBase,
                                                     int* __restrict__ svcnt, uint2* __restrict__ svrec) {
    if ((int)blockIdx.x >= nOrig) { phaseA_unit(unitBase + (int)blockIdx.x - nOrig, svcnt, svrec); return; }
    int c = blockIdx.x * 256 + threadIdx.x;
    double B0 = log((double)*sumdist) - 3.0;
    double t = exp(-exp((double)logits[c] - (B0 - 0.05)));
    long long k_th = (long long)floor(t * 8388608.0) - 2;
    uint32_t b;
    if (k_th <= 0)              b = 0u;           // everything survives
    else if (k_th >= 8388608LL) b = 0xFFFFFFFFu;  // ~nothing survives (over-include, harmless)
    else                        b = (uint32_t)k_th << 9;
    bth[c] = b;
    if (b < TH_SPEC) {
        int idx = atomicAdd(hotcnt, 1);
        hotlist[idx] = c;
    }
}

// ---------------- K3f: per-row fused band-scan + argmax + exactness check + table insert ----------------
// 256 threads/row. Band candidates (bth <= bits < TH_SPEC) collected in LDS;
// argmax over spec records + band. Exact: winner v > B0-0.05 => recorded; else full scan.
__global__ __launch_bounds__(256) void k_finalize(const float* __restrict__ logits,
                                                 const float* __restrict__ sumdist,
                                                 const int* __restrict__ svcnt,
                                                 const uint2* __restrict__ svrec,
                                                 const uint32_t* __restrict__ bth,
                                                 const int* __restrict__ hotlist,
                                                 const int* __restrict__ hotcnt,
                                                 const int* __restrict__ yidx,
                                                 int* __restrict__ hkeys,
                                                 int* __restrict__ samples) {
    int k = blockIdx.x;
    int tid = threadIdx.x;
    __shared__ uint2 band[BANDCAP];
    __shared__ int bandcnt;
    __shared__ float sv[256];
    __shared__ int   si[256];
    if (tid == 0) bandcnt = 0;
    __syncthreads();
    uint32_t base = (uint32_t)k * (uint32_t)CCLS;
    int nhot = *hotcnt;
    for (int j = tid; j < nhot; j += 256) {
        int c = hotlist[j];
        uint32_t bits = tf_bits(base + (uint32_t)c);
        if (bits >= bth[c] && bits < TH_SPEC) {
            int idx = atomicAdd(&bandcnt, 1);
            if (idx < BANDCAP) band[idx] = make_uint2((uint32_t)c, bits);
        }
    }
    __syncthreads();
    int n  = svcnt[k];
    int nb = bandcnt;
    double B0 = log((double)*sumdist) - 3.0;
    float best = -INFINITY; int bc = 0x7fffffff;
    bool full = (n > SVCAP) || (nb > BANDCAP);
    if (!full) {
        for (int j = tid; j < n; j += 256) {
            uint2 rec = svrec[k * SVCAP + j];
            int c = (int)rec.x;
            float v = __fadd_rn(gumbel_from_u(uniform_from_bits(rec.y)), logits[c]);
            if (v > best || (v == best && c < bc)) { best = v; bc = c; }
        }
        for (int j = tid; j < nb; j += 256) {
            uint2 rec = band[j];
            int c = (int)rec.x;
            float v = __fadd_rn(gumbel_from_u(uniform_from_bits(rec.y)), logits[c]);
            if (v > best || (v == best && c < bc)) { best = v; bc = c; }
        }
        sv[tid] = best; si[tid] = bc; __syncthreads();
        for (int off = 128; off > 0; off >>= 1) {
            if (tid < off) {
                float v2 = sv[tid+off]; int i2 = si[tid+off];
                if (v2 > sv[tid] || (v2 == sv[tid] && i2 < si[tid])) { sv[tid] = v2; si[tid] = i2; }
            }
            __syncthreads();
        }
        best = sv[0]; bc = si[0];
        __syncthreads();   // all reads of sv[0]/si[0] done before any LDS reuse
        if (!((double)best > B0 - 0.05)) full = true;   // winner might be unrecorded
    }
    if (full) {
        best = -INFINITY; bc = 0x7fffffff;
        for (int c = tid; c < CCLS; c += 256) {
            float v = __fadd_rn(gumbel_from_u(uniform_from_bits(tf_bits(base + (uint32_t)c))), logits[c]);
            if (v > best || (v == best && c < bc)) { best = v; bc = c; }
        }
        sv[tid] = best; si[tid] = bc; __syncthreads();
        for (int off = 128; off > 0; off >>= 1) {
            if (tid < off) {
                float v2 = sv[tid+off]; int i2 = si[tid+off];
                if (v2 > sv[tid] || (v2 == sv[tid] && i2 < si[tid])) { sv[tid] = v2; si[tid] = i2; }
            }
            __syncthreads();
        }
        best = sv[0]; bc = si[0];
    }
    if (tid == 0) {
        samples[k] = bc;
        // hash insert; empty sentinel = 0, stored key = flat+1 (zeroed in main memset)
        int xi = bc / GZD, zi = bc % GZD;
        int yi = yidx[bc];
        int key = (xi*GYD + yi)*GZD + zi + 1;
        uint32_t h = cell_hash(key - 1);
        for (;;) {
            int prev = atomicCAS(&hkeys[h], 0, key);
            if (prev == 0 || prev == key) break;
            h = (h + 1) & (HSLOTS - 1);
        }
    }
}

// ---------------- K3c: record-driven scale accumulation (no ballast: runs post-finalize) ----------------
__global__ __launch_bounds__(256) void k_scale_b(const int* __restrict__ binbase,
                          const int* __restrict__ bincnt,
                          const uint32_t* __restrict__ vrec,
                          const float* __restrict__ prob, const float* __restrict__ scale,
                          const int* __restrict__ hkeys, float* __restrict__ gsmall) {
    __shared__ int lk[HSLOTS];
    for (int j = threadIdx.x; j < HSLOTS; j += 256) lk[j] = hkeys[j];
    __syncthreads();
    int b = blockIdx.x;
    int x = b >> 1, ybit = b & 1;
    int fbase = x * SLICE + ybit * (YH*GZD) + 1;   // +1: stored keys are flat+1
    int lo = binbase[b], n = bincnt[b];
    for (int j = lo + threadIdx.x; j < lo + n; j += 256) {
        uint32_t rec = vrec[j];
        int key = fbase + (int)(rec & 0x3FFFu);
        uint32_t h = cell_hash(key - 1);
        int slot = -1;
        for (;;) {
            int kk = lk[h];
            if (kk == key) { slot = (int)h; break; }
            if (kk == 0) break;
            h = (h + 1) & (HSLOTS - 1);
        }
        if (slot < 0) continue;
        int i = (int)(rec >> 14);
        float w0 = prob[i];
        atomicAdd(&gsmall[3*slot+0], __fmul_rn(w0, scale[3*i]));
        atomicAdd(&gsmall[3*slot+1], __fmul_rn(w0, scale[3*i+1]));
        atomicAdd(&gsmall[3*slot+2], __fmul_rn(w0, scale[3*i+2]));
    }
}

// ---------------- K4: one block per sample — world loc, scale, keep ----------------
__global__ __launch_bounds__(256) void k_post(const unsigned long long* __restrict__ packed,
                       const int* __restrict__ hkeys, const float* __restrict__ gsmall,
                       const int* __restrict__ yidx, const int* __restrict__ samples,
                       const float* __restrict__ corners, const float* __restrict__ vp, int M,
                       float* __restrict__ world, float* __restrict__ scv, int* __restrict__ keep) {
    int k = blockIdx.x;
    int tid = threadIdx.x;
    int s = samples[k];
    int xi = s / GZD, zi = s % GZD;
    int yi = yidx[s];
    float wx = __fadd_rn(__fmul_rn((float)xi, 0.03f), corners[0]);
    float wy = __fadd_rn(__fmul_rn((float)yi, 0.03f), corners[1]);
    float wz = __fadd_rn(__fmul_rn((float)zi, 0.03f), corners[2]);

    float dmin = INFINITY;
    for (int j = tid; j < M; j += 256) {
        float dx = __fsub_rn(wx, vp[3*j]);
        float dy = __fsub_rn(wy, vp[3*j+1]);
        float dz = __fsub_rn(wz, vp[3*j+2]);
        float sq = __fadd_rn(__fadd_rn(__fmul_rn(dx,dx), __fmul_rn(dy,dy)), __fmul_rn(dz,dz));
        dmin = fminf(dmin, __fsqrt_rn(sq));
    }
    __shared__ float sm[256];
    sm[tid] = dmin; __syncthreads();
    for (int off = 128; off > 0; off >>= 1) {
        if (tid < off) sm[tid] = fminf(sm[tid], sm[tid+off]);
        __syncthreads();
    }
    if (tid == 0) {
        world[3*k] = wx; world[3*k+1] = wy; world[3*k+2] = wz;
        int key = (xi*GYD + yi)*GZD + zi + 1;
        uint32_t h = cell_hash(key - 1);
        while (hkeys[h] != key) h = (h + 1) & (HSLOTS - 1);  // guaranteed present
        float m = __uint_as_float((uint32_t)(packed[s] >> 32));
        float go = __fadd_rn(m, 1e-7f);
        scv[3*k+0] = __fdiv_rn(gsmall[3*h+0], go);
        scv[3*k+1] = __fdiv_rn(gsmall[3*h+1], go);
        scv[3*k+2] = __fdiv_rn(gsmall[3*h+2], go);
        keep[k] = (sm[0] < 0.3f) ? 1 : 0;
    }
}

// ---------------- K5: stable 0/1 selection via parallel prefix-sum ----------------
__global__ __launch_bounds__(256) void k_select(const float* __restrict__ world,
                                                const float* __restrict__ scv,
                                                const int* __restrict__ keep,
                                                float* __restrict__ out) {
    __shared__ int kp[KSMP];
    __shared__ int tsum[256];
    __shared__ int sel[NPROP];
    __shared__ int anyk;
    int tid = threadIdx.x;
    if (tid == 0) anyk = 0;
    __syncthreads();
    int a = 0;
    for (int j = tid; j < KSMP; j += 256) { int v = keep[j]; kp[j] = v; a |= v; }
    if (a) anyk = 1;           // benign race, all writers store 1
    __syncthreads();
    int any = anyk;
    int j0 = tid * 4;
    int k0v = any ? kp[j0]   : 1;
    int k1v = any ? kp[j0+1] : 1;
    int k2v = any ? kp[j0+2] : 1;
    int k3v = any ? kp[j0+3] : 1;
    int s0 = k0v, s1 = s0 + k1v, s2 = s1 + k2v, s3 = s2 + k3v;
    tsum[tid] = s3;
    __syncthreads();
    for (int off = 1; off < 256; off <<= 1) {
        int x = tsum[tid];
        if (tid >= off) x += tsum[tid - off];
        __syncthreads();
        tsum[tid] = x;
        __syncthreads();
    }
    int base = (tid > 0) ? tsum[tid-1] : 0;
    int nk = tsum[255];  // total kept
    int inc[4] = { base + s0, base + s1, base + s2, base + s3 };
    int kv[4]  = { k0v, k1v, k2v, k3v };
    for (int q = 0; q < 4; ++q) {
        int j = j0 + q;
        int slot = kv[q] ? (inc[q] - 1) : (nk + j - inc[q]);
        if (slot < NPROP) sel[slot] = j;
    }
    __syncthreads();
    if (tid < NPROP) {
        int sidx = sel[tid];
        out[3*tid+0] = world[3*sidx+0];
        out[3*tid+1] = world[3*sidx+1];
        out[3*tid+2] = world[3*sidx+2];
        out[3*NPROP + tid] = 0.0f;                 // probs
        out[4*NPROP + 3*tid + 0] = scv[3*sidx+0];
        out[4*NPROP + 3*tid + 1] = scv[3*sidx+1];
        out[4*NPROP + 3*tid + 2] = scv[3*sidx+2];
    }
}

extern "C" void kernel_launch(void* const* d_in, const int* in_sizes, int n_in,
                              void* d_out, int out_size, void* d_ws, size_t ws_size,
                              hipStream_t stream) {
    const float* pc      = (const float*)d_in[0];
    const float* xyz     = (const float*)d_in[1];
    const float* scale   = (const float*)d_in[2];
    const float* prob    = (const float*)d_in[3];
    const float* corners = (const float*)d_in[4];
    const float* vp      = (const float*)d_in[5];
    int N = in_sizes[0] / 3;
    int M = in_sizes[5] / 3;
    int pblocks = (N + 255) / 256;
    int NV = pblocks * 256 * NROT;   // vcache/vrec capacity (full blocks)
    if (N > (1 << 17)) {   // vrec packing requires i < 2^17 (ref N = 100000)
        fprintf(stderr, "kernel_launch: N %d exceeds packing limit\n", N);
        return;
    }

    // ---- zeroed region (single memset): sumdist..gsmall + hkeys (0-sentinel) ----
    float* sumdist = (float*)d_ws;                     // 1
    int*   bincnt  = (int*)(sumdist + 1);              // NBINS
    int*   svcnt   = bincnt + NBINS;                   // KSMP
    int*   hotcnt  = svcnt + KSMP;                     // 1 (also 8B-align pad)
    unsigned long long* packed = (unsigned long long*)(hotcnt + 1);  // CCLS u64
    float* gsmall  = (float*)(packed + CCLS);          // 3*HSLOTS
    int*   hkeys   = (int*)(gsmall + 3*HSLOTS);        // HSLOTS (0 = empty)
    size_t zero_bytes = (size_t)((char*)(hkeys + HSLOTS) - (char*)sumdist);
    // ---- rest ----
    int*   binbase = hkeys + HSLOTS;
    int*   bincur  = binbase + NBINS;
    float* logits  = (float*)(bincur + NBINS);
    uint32_t* bth  = (uint32_t*)(logits + CCLS);
    int*   yidx    = (int*)(bth + CCLS);
    int*   samples = yidx + CCLS;
    float* world   = (float*)(samples + KSMP);
    float* scv     = world + 3*KSMP;
    int*   keep    = (int*)(scv + 3*KSMP);
    uint2* svrec   = (uint2*)(((uintptr_t)(keep + KSMP) + 15) & ~(uintptr_t)15);
    int*   hotlist = (int*)(svrec + (size_t)KSMP * SVCAP);   // CCLS
    int*   hblk    = hotlist + CCLS;                         // pblocks*NBINS
    uint32_t* vcache = (uint32_t*)(((uintptr_t)(hblk + (size_t)pblocks*NBINS) + 15) & ~(uintptr_t)15);
    uint32_t* vrec = vcache + NV;
    size_t need = (size_t)((char*)(vrec + NV) - (char*)d_ws);
    if (ws_size < need) {
        fprintf(stderr, "kernel_launch: ws_size %zu < needed %zu\n", ws_size, need);
        return;
    }

    hipMemsetAsync(sumdist, 0, zero_bytes, stream);    // single memset (~630 KB)

    // rotation table: f32 theta chain exactly as reference, cos/sin in double -> f32
    RotTab rt;
    const float twopi = (float)(2.0 * M_PI);
    for (int r = 0; r < NROT; ++r) {
        float th = (twopi * (float)r) / 36.0f;
        rt.c[r] = (float)cos((double)th);
        rt.s[r] = (float)sin((double)th);
    }

    // phase-A ballast: ALL units on the four PRE-finalize hosts (sum == AUNITS = 9248)
    const int BAL1 = 2800, BAL2 = 2800, BAL3 = 1900;
    const int BAL4 = AUNITS - BAL1 - BAL2 - BAL3;   // 1748

    k_count_b<<<pblocks + BAL1, 256, 0, stream>>>(pc, xyz, corners, N, rt, bincnt, hblk, vcache,
                                                  pblocks, 0, svcnt, svrec);
    k_prefix<<<1, 576, 0, stream>>>(bincnt, binbase, bincur);
    k_binwrite_b<<<pblocks + BAL2, 256, 0, stream>>>(N, bincur, hblk, vcache, vrec,
                                                     pblocks, BAL1, svcnt, svrec);
    k_accum<<<NBINS, 256, 0, stream>>>(binbase, bincnt, vrec, prob, packed);
    k_colmax2_b<<<CBLK + BAL3, 256, 0, stream>>>(packed, logits, yidx, sumdist,
                                                 CBLK, BAL1 + BAL2, svcnt, svrec);
    k_hotthresh_b<<<CBLK + BAL4, 256, 0, stream>>>(logits, sumdist, bth, hotcnt, hotlist,
                                                   CBLK, BAL1 + BAL2 + BAL3, svcnt, svrec);
    k_finalize<<<KSMP, 256, 0, stream>>>(logits, sumdist, svcnt, svrec, bth, hotlist, hotcnt,
                                         yidx, hkeys, samples);
    k_scale_b<<<NBINS, 256, 0, stream>>>(binbase, bincnt, vrec, prob, scale, hkeys, gsmall);
    k_post<<<KSMP, 256, 0, stream>>>(packed, hkeys, gsmall, yidx, samples, corners, vp, M, world, scv, keep);
    k_select<<<1, 256, 0, stream>>>(world, scv, keep, (float*)d_out);
}